// Round 3
// baseline (406.232 us; speedup 1.0000x reference)
//
#include <hip/hip_runtime.h>

#define BB 8
#define TT 1024
#define DD 512
#define DD2 1024
#define HH 8
#define HDIM 64
#define TP (TT + 2)
#define PSTRIDE 136  // P-tile row stride in shorts: 136*2B=272B=68 dw -> 2-way (free) frag reads

typedef short short8 __attribute__((ext_vector_type(8)));
typedef float floatx4 __attribute__((ext_vector_type(4)));

typedef const __attribute__((address_space(1))) unsigned int* gas_ptr;
typedef __attribute__((address_space(3))) unsigned int* las_ptr;

__device__ __forceinline__ unsigned short f2bf(float f) {
    union { float f; unsigned u; } v; v.f = f;
    unsigned r = v.u + 0x7fffu + ((v.u >> 16) & 1u);
    return (unsigned short)(r >> 16);
}

// async global->LDS, 16B per lane, LDS dst = wave-uniform base + lane*16
__device__ __forceinline__ void gl2lds16(const void* g, void* l) {
    __builtin_amdgcn_global_load_lds((gas_ptr)g, (las_ptr)l, 16, 0, 0);
}

// ---------------- prep kernels ----------------
__global__ void k_convert_x(const float* __restrict__ x, unsigned short* __restrict__ xp) {
    int idx = blockIdx.x * 256 + threadIdx.x;
    const int total = BB * TP * DD;
    if (idx >= total) return;
    int c = idx % DD;
    int rt = idx / DD;
    int row = rt % TP;
    int b = rt / TP;
    float v = 0.f;
    if (row >= 1 && row <= TT) v = x[(b * TT + row - 1) * DD + c];
    xp[idx] = f2bf(v);
}

__global__ void k_convert_wqkv(const float* __restrict__ w0, const float* __restrict__ w1,
                               const float* __restrict__ w2, unsigned short* __restrict__ out) {
    int idx = blockIdx.x * 256 + threadIdx.x;
    const int total = 3 * 3 * DD * DD;
    if (idx >= total) return;
    int ci = idx % DD;
    int t1 = idx / DD;
    int co = t1 % DD;
    int t2 = t1 / DD;
    int k = t2 % 3;
    int p = t2 / 3;
    const float* w = (p == 0) ? w0 : ((p == 1) ? w1 : w2);
    out[idx] = f2bf(w[(co * DD + ci) * 3 + k]);
}

__global__ void k_convert_w2(const float* __restrict__ w, unsigned short* __restrict__ out) {
    int idx = blockIdx.x * 256 + threadIdx.x;
    const int total = 3 * DD * DD2;
    if (idx >= total) return;
    int ci = idx % DD2;
    int t1 = idx / DD2;
    int co = t1 % DD;
    int k = t1 / DD;
    out[idx] = f2bf(w[(co * DD2 + ci) * 3 + k]);
}

__global__ void k_zero_aux(unsigned short* __restrict__ vp, float* __restrict__ gbuf) {
    int idx = blockIdx.x * 256 + threadIdx.x;
    if (idx < BB * 2 * 2 * DD) {
        int c = idx % (2 * DD);
        int t1 = idx / (2 * DD);
        int row = (t1 & 1) ? (TT + 1) : 0;
        int b = t1 >> 1;
        vp[(b * TP + row) * (2 * DD) + c] = 0;
    }
    if (idx < 64 * HDIM * HDIM) gbuf[idx] = 0.f;
}

// ---------------- QKV conv: m97-style 128x128 tile, BK=32, LDS staged ----------------
// grid (T/128=8, 512/128=4, B*3=24), 256 thr = 4 waves (2x2), wave tile 64x64
__global__ __launch_bounds__(256) void k_qkv_conv(
    const unsigned short* __restrict__ xp, const unsigned short* __restrict__ wqkv,
    const float* __restrict__ b11, const float* __restrict__ b12, const float* __restrict__ b13,
    unsigned short* __restrict__ q, unsigned short* __restrict__ qt,
    unsigned short* __restrict__ kbuf, unsigned short* __restrict__ kt,
    unsigned short* __restrict__ v, unsigned short* __restrict__ vt) {
    __shared__ short As[144 * 32];      // rows tb..tb+143 (halo; only 0..129 used)
    __shared__ short Ws[3 * 128 * 32];  // [k][co 128][ci 32]
    int wave = threadIdx.x >> 6, lane = threadIdx.x & 63;
    int l15 = lane & 15, quad = lane >> 4;
    int wm = wave >> 1, wn = wave & 1;
    int tb = blockIdx.x * 128;
    int cb = blockIdx.y * 128;
    int proj = blockIdx.z % 3, b = blockIdx.z / 3;
    const short* A = (const short*)xp + b * TP * DD;
    const short* W = (const short*)wqkv + proj * 3 * DD * DD;
    int srow = lane >> 2;       // staging: lane -> row 0..15
    int scol = (lane & 3) * 8;  // staging: lane -> col (8 bf16 = 16B)

    floatx4 acc[4][4];
#pragma unroll
    for (int mi = 0; mi < 4; ++mi)
#pragma unroll
        for (int ni = 0; ni < 4; ++ni) acc[mi][ni] = (floatx4){0.f, 0.f, 0.f, 0.f};

    for (int ci = 0; ci < DD; ci += 32) {
        if (ci) __syncthreads();
        for (int j = wave; j < 33; j += 4) {
            if (j < 9) {
                gl2lds16(A + (tb + j * 16 + srow) * DD + ci + scol, &As[j * 512]);
            } else {
                int jj = j - 9;
                int k = jj >> 3;
                gl2lds16(W + k * DD * DD + (cb + (jj & 7) * 16 + srow) * DD + ci + scol,
                         &Ws[jj * 512]);
            }
        }
        __syncthreads();
#pragma unroll
        for (int k = 0; k < 3; ++k) {
            short8 af[4], bf[4];
#pragma unroll
            for (int mi = 0; mi < 4; ++mi)
                af[mi] = *(const short8*)&As[(wm * 64 + mi * 16 + l15 + k) * 32 + quad * 8];
#pragma unroll
            for (int ni = 0; ni < 4; ++ni)
                bf[ni] = *(const short8*)&Ws[(k * 128 + wn * 64 + ni * 16 + l15) * 32 + quad * 8];
#pragma unroll
            for (int mi = 0; mi < 4; ++mi)
#pragma unroll
                for (int ni = 0; ni < 4; ++ni)
                    acc[mi][ni] = __builtin_amdgcn_mfma_f32_16x16x32_bf16(af[mi], bf[ni], acc[mi][ni], 0, 0, 0);
        }
    }

    const float* bias = (proj == 0) ? b11 : ((proj == 1) ? b12 : b13);
    unsigned short* o1 = (proj == 0) ? q : ((proj == 1) ? kbuf : v);
    unsigned short* o2 = (proj == 0) ? qt : ((proj == 1) ? kt : vt);
#pragma unroll
    for (int ni = 0; ni < 4; ++ni) {
        int co = cb + wn * 64 + ni * 16 + l15;
        float bv = bias[co];
        int h = co >> 6, hd = co & 63;
#pragma unroll
        for (int mi = 0; mi < 4; ++mi) {
#pragma unroll
            for (int r = 0; r < 4; ++r) {
                int t = tb + wm * 64 + mi * 16 + quad * 4 + r;
                float val = fmaxf(acc[mi][ni][r] + bv, 0.f);
                unsigned short bb = f2bf(val);
                o1[((b * HH + h) * TT + t) * HDIM + hd] = bb;
                o2[((b * HH + h) * HDIM + hd) * TT + t] = bb;
            }
        }
    }
}

// ---------------- time attention (flash-style, S^T layout, 128-wide steps) ----------------
// grid (T/64=16, B*H=64), block 256; each wave owns 16 Q rows.
// S^T = K.Q^T so each lane's scores belong to one q (=l15): row-max = in-reg tree
// + 2 shuffles; P packs to s-contiguous b64 LDS writes; row-sum via ones-column MFMA.
__global__ __launch_bounds__(256) void k_time_attn(
    const unsigned short* __restrict__ q, const unsigned short* __restrict__ kbuf,
    const unsigned short* __restrict__ vt, unsigned short* __restrict__ vp) {
    __shared__ short lds_p[4][16 * PSTRIDE];
    int wave = threadIdx.x >> 6, lane = threadIdx.x & 63;
    int l15 = lane & 15, quad = lane >> 4;
    int bh = blockIdx.y;
    int b = bh >> 3, h = bh & 7;
    int qr = blockIdx.x * 64 + wave * 16;
    const short* Q = (const short*)q + bh * TT * HDIM;
    const short* K = (const short*)kbuf + bh * TT * HDIM;
    const short* Vt = (const short*)vt + bh * HDIM * TT;
    short* Pw = lds_p[wave];

    // Q as B-operand fragments (n = q rows)
    short8 bq[2];
#pragma unroll
    for (int kf = 0; kf < 2; ++kf)
        bq[kf] = *(const short8*)(Q + (qr + l15) * HDIM + kf * 32 + quad * 8);

    // ones column fragment: B[n=0][k] = 1
    short ov = (l15 == 0) ? (short)0x3F80 : (short)0;
    short8 bones = {ov, ov, ov, ov, ov, ov, ov, ov};

    floatx4 o[5];  // o[0..3] = d columns, o[4] col0 = running row-sum l
#pragma unroll
    for (int df = 0; df < 5; ++df) o[df] = (floatx4){0.f, 0.f, 0.f, 0.f};
    float mrow = -3.0e38f;  // running max for q = l15

    for (int s = 0; s < TT; s += 128) {
        floatx4 c[8];
#pragma unroll
        for (int jr = 0; jr < 8; ++jr) c[jr] = (floatx4){0.f, 0.f, 0.f, 0.f};
#pragma unroll
        for (int kf = 0; kf < 2; ++kf) {
#pragma unroll
            for (int jr = 0; jr < 8; ++jr) {
                short8 ak = *(const short8*)(K + (s + jr * 16 + l15) * HDIM + kf * 32 + quad * 8);
                c[jr] = __builtin_amdgcn_mfma_f32_16x16x32_bf16(ak, bq[kf], c[jr], 0, 0, 0);
            }
        }
        // in-lane max over all 32 scores (q = l15 fixed)
        float mt = c[0][0];
#pragma unroll
        for (int jr = 0; jr < 8; ++jr)
#pragma unroll
            for (int r = 0; r < 4; ++r) mt = fmaxf(mt, c[jr][r]);
        mt *= 0.125f;
        mt = fmaxf(mt, __shfl_xor(mt, 16));
        mt = fmaxf(mt, __shfl_xor(mt, 32));
        float mn = fmaxf(mrow, mt);
        float alpha = __expf(mrow - mn);
        mrow = mn;
        // exp, pack 2x bf16 (trunc) per v_perm, store b64: P[q=l15][s=16jr+4quad+r]
#pragma unroll
        for (int jr = 0; jr < 8; ++jr) {
            float p0 = __expf(c[jr][0] * 0.125f - mn);
            float p1 = __expf(c[jr][1] * 0.125f - mn);
            float p2 = __expf(c[jr][2] * 0.125f - mn);
            float p3 = __expf(c[jr][3] * 0.125f - mn);
            unsigned d0 = __builtin_amdgcn_perm(__float_as_uint(p1), __float_as_uint(p0), 0x07060302u);
            unsigned d1 = __builtin_amdgcn_perm(__float_as_uint(p3), __float_as_uint(p2), 0x07060302u);
            *(unsigned long long*)&Pw[l15 * PSTRIDE + jr * 16 + quad * 4] =
                ((unsigned long long)d1 << 32) | d0;
        }
        // alpha from softmax layout (lane l15=q) to O layout (row q = quad*4+r)
        float alpha_o[4];
#pragma unroll
        for (int r = 0; r < 4; ++r) alpha_o[r] = __shfl(alpha, quad * 4 + r);
#pragma unroll
        for (int df = 0; df < 5; ++df)
#pragma unroll
            for (int r = 0; r < 4; ++r) o[df][r] *= alpha_o[r];
        // P.V (A = P from LDS, B = Vt rows + ones column)
#pragma unroll
        for (int kf = 0; kf < 4; ++kf) {
            short8 pa = *(const short8*)&Pw[l15 * PSTRIDE + kf * 32 + quad * 8];
#pragma unroll
            for (int df = 0; df < 4; ++df) {
                short8 bv = *(const short8*)(Vt + (df * 16 + l15) * TT + s + kf * 32 + quad * 8);
                o[df] = __builtin_amdgcn_mfma_f32_16x16x32_bf16(pa, bv, o[df], 0, 0, 0);
            }
            o[4] = __builtin_amdgcn_mfma_f32_16x16x32_bf16(pa, bones, o[4], 0, 0, 0);
        }
    }

    float linv[4];
#pragma unroll
    for (int r = 0; r < 4; ++r) {
        float lsum = __shfl(o[4][r], quad * 16);  // row-sum lives in l15==0 of same quad
        linv[r] = 1.f / lsum;
    }
#pragma unroll
    for (int r = 0; r < 4; ++r) {
        int t = qr + quad * 4 + r;
#pragma unroll
        for (int df = 0; df < 4; ++df) {
            vp[(b * TP + 1 + t) * (2 * DD) + h * 64 + df * 16 + l15] = f2bf(o[df][r] * linv[r]);
        }
    }
}

// ---------------- channel attention: Gram partials (4-way T split) ----------------
// grid (4, B*H=64), block 256; wave w owns c-rows [16w,16w+16)
__global__ __launch_bounds__(256) void k_chan_gram(
    const unsigned short* __restrict__ qt, const unsigned short* __restrict__ kt,
    float* __restrict__ gbuf) {
    int wave = threadIdx.x >> 6, lane = threadIdx.x & 63;
    int l15 = lane & 15, quad = lane >> 4;
    int tc = blockIdx.x, bh = blockIdx.y;
    const short* Qt = (const short*)qt + bh * HDIM * TT;
    const short* Kt = (const short*)kt + bh * HDIM * TT;

    floatx4 g[4];
#pragma unroll
    for (int nt = 0; nt < 4; ++nt) g[nt] = (floatx4){0.f, 0.f, 0.f, 0.f};

    int t0b = tc * 256;
    for (int t0 = 0; t0 < 256; t0 += 32) {
        short8 aq = *(const short8*)(Qt + (wave * 16 + l15) * TT + t0b + t0 + quad * 8);
#pragma unroll
        for (int nt = 0; nt < 4; ++nt) {
            short8 bk = *(const short8*)(Kt + (nt * 16 + l15) * TT + t0b + t0 + quad * 8);
            g[nt] = __builtin_amdgcn_mfma_f32_16x16x32_bf16(aq, bk, g[nt], 0, 0, 0);
        }
    }
    float* gb = gbuf + bh * HDIM * HDIM;
#pragma unroll
    for (int nt = 0; nt < 4; ++nt) {
#pragma unroll
        for (int r = 0; r < 4; ++r) {
            int row = wave * 16 + quad * 4 + r;
            atomicAdd(&gb[row * HDIM + nt * 16 + l15], g[nt][r]);
        }
    }
}

// ---------------- channel attention: softmax + A.V (4-way T split) ----------------
// grid (4, B*H=64), block 256
__global__ __launch_bounds__(256) void k_chan_av(
    const float* __restrict__ gbuf, const unsigned short* __restrict__ v,
    unsigned short* __restrict__ vp) {
    __shared__ short lds_a[64 * 64];
    int wave = threadIdx.x >> 6, lane = threadIdx.x & 63;
    int l15 = lane & 15, quad = lane >> 4;
    int tc = blockIdx.x, bh = blockIdx.y;
    int b = bh >> 3, h = bh & 7;
    const float sc = 0.03125f;  // 1/sqrt(1024)

    if (threadIdx.x < 64) {
        const float* gb = gbuf + bh * HDIM * HDIM + threadIdx.x * HDIM;
        float mx = -3.0e38f;
        for (int j = 0; j < 64; ++j) mx = fmaxf(mx, gb[j] * sc);
        float sum = 0.f;
        for (int j = 0; j < 64; ++j) sum += __expf(gb[j] * sc - mx);
        float inv = 1.f / sum;
        for (int j = 0; j < 64; ++j)
            lds_a[threadIdx.x * 64 + j] = (short)f2bf(__expf(gb[j] * sc - mx) * inv);
    }
    __syncthreads();

    const short* V = (const short*)v + bh * TT * HDIM;
    short8 pa[2];
#pragma unroll
    for (int kf = 0; kf < 2; ++kf)
        pa[kf] = *(const short8*)&lds_a[(wave * 16 + l15) * 64 + kf * 32 + quad * 8];

    for (int tt = 0; tt < 16; ++tt) {
        int ttile = tc * 16 + tt;
        floatx4 c = (floatx4){0.f, 0.f, 0.f, 0.f};
#pragma unroll
        for (int kf = 0; kf < 2; ++kf) {
            short8 bv = *(const short8*)(V + (ttile * 16 + l15) * HDIM + kf * 32 + quad * 8);
            c = __builtin_amdgcn_mfma_f32_16x16x32_bf16(pa[kf], bv, c, 0, 0, 0);
        }
        int t = ttile * 16 + l15;
#pragma unroll
        for (int r = 0; r < 4; ++r) {
            int crow = wave * 16 + quad * 4 + r;
            int tout = crow * 16 + (t >> 6);
            int col = 512 + ((t & 63) << 3) + h;
            vp[(b * TP + 1 + tout) * (2 * DD) + col] = f2bf(c[r]);
        }
    }
}

// ---------------- output conv: 128x128 tile, BK=32, LDS staged ----------------
// grid (T/128=8, 512/128=4, B=8)
__global__ __launch_bounds__(256) void k_out_conv(
    const unsigned short* __restrict__ vp, const unsigned short* __restrict__ w2k,
    const float* __restrict__ b2, float* __restrict__ out) {
    __shared__ short As[144 * 32];
    __shared__ short Ws[3 * 128 * 32];
    int wave = threadIdx.x >> 6, lane = threadIdx.x & 63;
    int l15 = lane & 15, quad = lane >> 4;
    int wm = wave >> 1, wn = wave & 1;
    int tb = blockIdx.x * 128;
    int cb = blockIdx.y * 128;
    int b = blockIdx.z;
    const short* A = (const short*)vp + b * TP * DD2;
    const short* W = (const short*)w2k;
    int srow = lane >> 2;
    int scol = (lane & 3) * 8;

    floatx4 acc[4][4];
#pragma unroll
    for (int mi = 0; mi < 4; ++mi)
#pragma unroll
        for (int ni = 0; ni < 4; ++ni) acc[mi][ni] = (floatx4){0.f, 0.f, 0.f, 0.f};

    for (int ci = 0; ci < DD2; ci += 32) {
        if (ci) __syncthreads();
        for (int j = wave; j < 33; j += 4) {
            if (j < 9) {
                gl2lds16(A + (tb + j * 16 + srow) * DD2 + ci + scol, &As[j * 512]);
            } else {
                int jj = j - 9;
                int k = jj >> 3;
                gl2lds16(W + (k * DD + cb + (jj & 7) * 16 + srow) * DD2 + ci + scol,
                         &Ws[jj * 512]);
            }
        }
        __syncthreads();
#pragma unroll
        for (int k = 0; k < 3; ++k) {
            short8 af[4], bf[4];
#pragma unroll
            for (int mi = 0; mi < 4; ++mi)
                af[mi] = *(const short8*)&As[(wm * 64 + mi * 16 + l15 + k) * 32 + quad * 8];
#pragma unroll
            for (int ni = 0; ni < 4; ++ni)
                bf[ni] = *(const short8*)&Ws[(k * 128 + wn * 64 + ni * 16 + l15) * 32 + quad * 8];
#pragma unroll
            for (int mi = 0; mi < 4; ++mi)
#pragma unroll
                for (int ni = 0; ni < 4; ++ni)
                    acc[mi][ni] = __builtin_amdgcn_mfma_f32_16x16x32_bf16(af[mi], bf[ni], acc[mi][ni], 0, 0, 0);
        }
    }

#pragma unroll
    for (int ni = 0; ni < 4; ++ni) {
        int co = cb + wn * 64 + ni * 16 + l15;
        float bv = b2[co];
#pragma unroll
        for (int mi = 0; mi < 4; ++mi) {
#pragma unroll
            for (int r = 0; r < 4; ++r) {
                int t = tb + wm * 64 + mi * 16 + quad * 4 + r;
                out[(b * TT + t) * DD + co] = fmaxf(acc[mi][ni][r] + bv, 0.f);
            }
        }
    }
}

extern "C" void kernel_launch(void* const* d_in, const int* in_sizes, int n_in,
                              void* d_out, int out_size, void* d_ws, size_t ws_size,
                              hipStream_t stream) {
    const float* x = (const float*)d_in[0];
    const float* w11 = (const float*)d_in[1];
    const float* b11 = (const float*)d_in[2];
    const float* w12 = (const float*)d_in[3];
    const float* b12 = (const float*)d_in[4];
    const float* w13 = (const float*)d_in[5];
    const float* b13 = (const float*)d_in[6];
    const float* w2 = (const float*)d_in[7];
    const float* b2 = (const float*)d_in[8];
    float* out = (float*)d_out;

    char* ws = (char*)d_ws;
    size_t off = 0;
    auto alloc = [&](size_t bytes) {
        void* p = ws + off;
        off += (bytes + 255) & ~(size_t)255;
        return p;
    };
    unsigned short* xp = (unsigned short*)alloc((size_t)BB * TP * DD * 2);
    unsigned short* wqkv = (unsigned short*)alloc((size_t)9 * DD * DD * 2);
    unsigned short* w2k = (unsigned short*)alloc((size_t)3 * DD * DD2 * 2);
    unsigned short* q = (unsigned short*)alloc((size_t)BB * HH * TT * HDIM * 2);
    unsigned short* qt = (unsigned short*)alloc((size_t)BB * HH * TT * HDIM * 2);
    unsigned short* k = (unsigned short*)alloc((size_t)BB * HH * TT * HDIM * 2);
    unsigned short* kt = (unsigned short*)alloc((size_t)BB * HH * TT * HDIM * 2);
    unsigned short* v = (unsigned short*)alloc((size_t)BB * HH * TT * HDIM * 2);
    unsigned short* vt = (unsigned short*)alloc((size_t)BB * HH * TT * HDIM * 2);
    float* gbuf = (float*)alloc((size_t)64 * HDIM * HDIM * 4);
    unsigned short* vp = (unsigned short*)alloc((size_t)BB * TP * 2 * DD * 2);
    (void)alloc(65536);  // guard: halo staging reads up to 14 rows past vp end

    k_convert_x<<<(BB * TP * DD + 255) / 256, 256, 0, stream>>>(x, xp);
    k_convert_wqkv<<<(3 * 3 * DD * DD + 255) / 256, 256, 0, stream>>>(w11, w12, w13, wqkv);
    k_convert_w2<<<(3 * DD * DD2 + 255) / 256, 256, 0, stream>>>(w2, w2k);
    k_zero_aux<<<(64 * HDIM * HDIM + 255) / 256, 256, 0, stream>>>(vp, gbuf);
    k_qkv_conv<<<dim3(TT / 128, DD / 128, BB * 3), 256, 0, stream>>>(xp, wqkv, b11, b12, b13,
                                                                     q, qt, k, kt, v, vt);
    k_time_attn<<<dim3(TT / 64, BB * HH), 256, 0, stream>>>(q, k, vt, vp);
    k_chan_gram<<<dim3(4, BB * HH), 256, 0, stream>>>(qt, kt, gbuf);
    k_chan_av<<<dim3(4, BB * HH), 256, 0, stream>>>(gbuf, v, vp);
    k_out_conv<<<dim3(TT / 128, DD / 128, BB), 256, 0, stream>>>(vp, w2k, b2, out);
}

// Round 4
// 363.158 us; speedup vs baseline: 1.1186x; 1.1186x over previous
//
#include <hip/hip_runtime.h>

#define BB 8
#define TT 1024
#define DD 512
#define DD2 1024
#define HH 8
#define HDIM 64
#define TP (TT + 2)
#define PSTRIDE 72  // P row stride (shorts): 16B-aligned b128 frag reads, balanced banks

typedef short short8 __attribute__((ext_vector_type(8)));
typedef float floatx4 __attribute__((ext_vector_type(4)));

typedef const __attribute__((address_space(1))) unsigned int* gas_ptr;
typedef __attribute__((address_space(3))) unsigned int* las_ptr;

__device__ __forceinline__ unsigned short f2bf(float f) {
    union { float f; unsigned u; } v; v.f = f;
    unsigned r = v.u + 0x7fffu + ((v.u >> 16) & 1u);
    return (unsigned short)(r >> 16);
}

// async global->LDS, 16B per lane, LDS dst = wave-uniform base + lane*16
__device__ __forceinline__ void gl2lds16(const void* g, void* l) {
    __builtin_amdgcn_global_load_lds((gas_ptr)g, (las_ptr)l, 16, 0, 0);
}

// ---------------- prep kernels ----------------
__global__ void k_convert_x(const float* __restrict__ x, unsigned short* __restrict__ xp) {
    int idx = blockIdx.x * 256 + threadIdx.x;
    const int total = BB * TP * DD;
    if (idx >= total) return;
    int c = idx % DD;
    int rt = idx / DD;
    int row = rt % TP;
    int b = rt / TP;
    float v = 0.f;
    if (row >= 1 && row <= TT) v = x[(b * TT + row - 1) * DD + c];
    xp[idx] = f2bf(v);
}

__global__ void k_convert_wqkv(const float* __restrict__ w0, const float* __restrict__ w1,
                               const float* __restrict__ w2, unsigned short* __restrict__ out) {
    int idx = blockIdx.x * 256 + threadIdx.x;
    const int total = 3 * 3 * DD * DD;
    if (idx >= total) return;
    int ci = idx % DD;
    int t1 = idx / DD;
    int co = t1 % DD;
    int t2 = t1 / DD;
    int k = t2 % 3;
    int p = t2 / 3;
    const float* w = (p == 0) ? w0 : ((p == 1) ? w1 : w2);
    out[idx] = f2bf(w[(co * DD + ci) * 3 + k]);
}

__global__ void k_convert_w2(const float* __restrict__ w, unsigned short* __restrict__ out) {
    int idx = blockIdx.x * 256 + threadIdx.x;
    const int total = 3 * DD * DD2;
    if (idx >= total) return;
    int ci = idx % DD2;
    int t1 = idx / DD2;
    int co = t1 % DD;
    int k = t1 / DD;
    out[idx] = f2bf(w[(co * DD2 + ci) * 3 + k]);
}

__global__ void k_zero_aux(unsigned short* __restrict__ vp, float* __restrict__ gbuf) {
    int idx = blockIdx.x * 256 + threadIdx.x;
    if (idx < BB * 2 * 2 * DD) {
        int c = idx % (2 * DD);
        int t1 = idx / (2 * DD);
        int row = (t1 & 1) ? (TT + 1) : 0;
        int b = t1 >> 1;
        vp[(b * TP + row) * (2 * DD) + c] = 0;
    }
    if (idx < 64 * HDIM * HDIM) gbuf[idx] = 0.f;
}

// ---------------- QKV conv: m97-style 128x128 tile, BK=32, LDS staged ----------------
// grid (T/128=8, 512/128=4, B*3=24), 256 thr = 4 waves (2x2), wave tile 64x64
__global__ __launch_bounds__(256) void k_qkv_conv(
    const unsigned short* __restrict__ xp, const unsigned short* __restrict__ wqkv,
    const float* __restrict__ b11, const float* __restrict__ b12, const float* __restrict__ b13,
    unsigned short* __restrict__ q, unsigned short* __restrict__ qt,
    unsigned short* __restrict__ kbuf, unsigned short* __restrict__ kt,
    unsigned short* __restrict__ v, unsigned short* __restrict__ vt) {
    __shared__ short As[144 * 32];      // rows tb..tb+143 (halo; only 0..129 used)
    __shared__ short Ws[3 * 128 * 32];  // [k][co 128][ci 32]
    int wave = threadIdx.x >> 6, lane = threadIdx.x & 63;
    int l15 = lane & 15, quad = lane >> 4;
    int wm = wave >> 1, wn = wave & 1;
    int tb = blockIdx.x * 128;
    int cb = blockIdx.y * 128;
    int proj = blockIdx.z % 3, b = blockIdx.z / 3;
    const short* A = (const short*)xp + b * TP * DD;
    const short* W = (const short*)wqkv + proj * 3 * DD * DD;
    int srow = lane >> 2;       // staging: lane -> row 0..15
    int scol = (lane & 3) * 8;  // staging: lane -> col (8 bf16 = 16B)

    floatx4 acc[4][4];
#pragma unroll
    for (int mi = 0; mi < 4; ++mi)
#pragma unroll
        for (int ni = 0; ni < 4; ++ni) acc[mi][ni] = (floatx4){0.f, 0.f, 0.f, 0.f};

    for (int ci = 0; ci < DD; ci += 32) {
        if (ci) __syncthreads();
        for (int j = wave; j < 33; j += 4) {
            if (j < 9) {
                gl2lds16(A + (tb + j * 16 + srow) * DD + ci + scol, &As[j * 512]);
            } else {
                int jj = j - 9;
                int k = jj >> 3;
                gl2lds16(W + k * DD * DD + (cb + (jj & 7) * 16 + srow) * DD + ci + scol,
                         &Ws[jj * 512]);
            }
        }
        __syncthreads();
#pragma unroll
        for (int k = 0; k < 3; ++k) {
            short8 af[4], bf[4];
#pragma unroll
            for (int mi = 0; mi < 4; ++mi)
                af[mi] = *(const short8*)&As[(wm * 64 + mi * 16 + l15 + k) * 32 + quad * 8];
#pragma unroll
            for (int ni = 0; ni < 4; ++ni)
                bf[ni] = *(const short8*)&Ws[(k * 128 + wn * 64 + ni * 16 + l15) * 32 + quad * 8];
#pragma unroll
            for (int mi = 0; mi < 4; ++mi)
#pragma unroll
                for (int ni = 0; ni < 4; ++ni)
                    acc[mi][ni] = __builtin_amdgcn_mfma_f32_16x16x32_bf16(af[mi], bf[ni], acc[mi][ni], 0, 0, 0);
        }
    }

    const float* bias = (proj == 0) ? b11 : ((proj == 1) ? b12 : b13);
    unsigned short* o1 = (proj == 0) ? q : ((proj == 1) ? kbuf : v);
    unsigned short* o2 = (proj == 0) ? qt : ((proj == 1) ? kt : vt);
#pragma unroll
    for (int ni = 0; ni < 4; ++ni) {
        int co = cb + wn * 64 + ni * 16 + l15;
        float bv = bias[co];
        int h = co >> 6, hd = co & 63;
#pragma unroll
        for (int mi = 0; mi < 4; ++mi) {
            int tbase = tb + wm * 64 + mi * 16 + quad * 4;
            ushort4 pk;
#pragma unroll
            for (int r = 0; r < 4; ++r) {
                float val = fmaxf(acc[mi][ni][r] + bv, 0.f);
                unsigned short bb = f2bf(val);
                o1[((b * HH + h) * TT + tbase + r) * HDIM + hd] = bb;
                ((unsigned short*)&pk)[r] = bb;
            }
            *(ushort4*)&o2[((b * HH + h) * HDIM + hd) * TT + tbase] = pk;
        }
    }
}

// ---------------- time attention: no-max softmax (q,k >= 0 post-ReLU => s in [0,~25]) ----
// grid (T/64=16, B*H=64), block 256; each wave owns 16 Q rows; no barriers, no shuffles
// in the hot loop. P = exp(S/8) direct; l accumulated in-lane, reduced once at the end.
__global__ __launch_bounds__(256) void k_time_attn(
    const unsigned short* __restrict__ q, const unsigned short* __restrict__ kbuf,
    const unsigned short* __restrict__ vt, unsigned short* __restrict__ vp) {
    __shared__ short lds_p[4][16 * PSTRIDE];
    int wave = threadIdx.x >> 6, lane = threadIdx.x & 63;
    int l15 = lane & 15, quad = lane >> 4;
    int bh = blockIdx.y;
    int b = bh >> 3, h = bh & 7;
    int qr = blockIdx.x * 64 + wave * 16;
    const short* Q = (const short*)q + bh * TT * HDIM;
    const short* K = (const short*)kbuf + bh * TT * HDIM;
    const short* Vt = (const short*)vt + bh * HDIM * TT;
    short* Pw = lds_p[wave];

    short8 aq[2];
#pragma unroll
    for (int kf = 0; kf < 2; ++kf)
        aq[kf] = *(const short8*)(Q + (qr + l15) * HDIM + kf * 32 + quad * 8);

    floatx4 o[4];
#pragma unroll
    for (int df = 0; df < 4; ++df) o[df] = (floatx4){0.f, 0.f, 0.f, 0.f};
    float lacc[4] = {0.f, 0.f, 0.f, 0.f};

    for (int s = 0; s < TT; s += 64) {
        floatx4 c[4];
#pragma unroll
        for (int j = 0; j < 4; ++j) c[j] = (floatx4){0.f, 0.f, 0.f, 0.f};
#pragma unroll
        for (int kf = 0; kf < 2; ++kf) {
#pragma unroll
            for (int j = 0; j < 4; ++j) {
                short8 bk = *(const short8*)(K + (s + j * 16 + l15) * HDIM + kf * 32 + quad * 8);
                c[j] = __builtin_amdgcn_mfma_f32_16x16x32_bf16(aq[kf], bk, c[j], 0, 0, 0);
            }
        }
        // P = exp(S/8), no max subtraction (scores >= 0, bounded); l accumulates in fp32
#pragma unroll
        for (int j = 0; j < 4; ++j) {
#pragma unroll
            for (int r = 0; r < 4; ++r) {
                float p = __expf(c[j][r] * 0.125f);
                lacc[r] += p;
                Pw[(quad * 4 + r) * PSTRIDE + j * 16 + l15] = (short)f2bf(p);
            }
        }
        // P.V: A-frags from LDS (balanced banks, 16B aligned), B = Vt rows
#pragma unroll
        for (int kf = 0; kf < 2; ++kf) {
            short8 pa = *(const short8*)&Pw[l15 * PSTRIDE + kf * 32 + quad * 8];
#pragma unroll
            for (int df = 0; df < 4; ++df) {
                short8 bv = *(const short8*)(Vt + (df * 16 + l15) * TT + s + kf * 32 + quad * 8);
                o[df] = __builtin_amdgcn_mfma_f32_16x16x32_bf16(pa, bv, o[df], 0, 0, 0);
            }
        }
    }

    // reduce l across the 16 col-owner lanes within each quad (one-time cost)
    float linv[4];
#pragma unroll
    for (int r = 0; r < 4; ++r) {
        float ls = lacc[r];
        ls += __shfl_xor(ls, 1);
        ls += __shfl_xor(ls, 2);
        ls += __shfl_xor(ls, 4);
        ls += __shfl_xor(ls, 8);
        linv[r] = 1.f / ls;
    }
#pragma unroll
    for (int r = 0; r < 4; ++r) {
        int t = qr + quad * 4 + r;
#pragma unroll
        for (int df = 0; df < 4; ++df) {
            vp[(b * TP + 1 + t) * (2 * DD) + h * 64 + df * 16 + l15] = f2bf(o[df][r] * linv[r]);
        }
    }
}

// ---------------- channel attention: Gram partials (4-way T split) ----------------
// grid (4, B*H=64), block 256; wave w owns c-rows [16w,16w+16)
__global__ __launch_bounds__(256) void k_chan_gram(
    const unsigned short* __restrict__ qt, const unsigned short* __restrict__ kt,
    float* __restrict__ gbuf) {
    int wave = threadIdx.x >> 6, lane = threadIdx.x & 63;
    int l15 = lane & 15, quad = lane >> 4;
    int tc = blockIdx.x, bh = blockIdx.y;
    const short* Qt = (const short*)qt + bh * HDIM * TT;
    const short* Kt = (const short*)kt + bh * HDIM * TT;

    floatx4 g[4];
#pragma unroll
    for (int nt = 0; nt < 4; ++nt) g[nt] = (floatx4){0.f, 0.f, 0.f, 0.f};

    int t0b = tc * 256;
    for (int t0 = 0; t0 < 256; t0 += 32) {
        short8 aq = *(const short8*)(Qt + (wave * 16 + l15) * TT + t0b + t0 + quad * 8);
#pragma unroll
        for (int nt = 0; nt < 4; ++nt) {
            short8 bk = *(const short8*)(Kt + (nt * 16 + l15) * TT + t0b + t0 + quad * 8);
            g[nt] = __builtin_amdgcn_mfma_f32_16x16x32_bf16(aq, bk, g[nt], 0, 0, 0);
        }
    }
    float* gb = gbuf + bh * HDIM * HDIM;
#pragma unroll
    for (int nt = 0; nt < 4; ++nt) {
#pragma unroll
        for (int r = 0; r < 4; ++r) {
            int row = wave * 16 + quad * 4 + r;
            atomicAdd(&gb[row * HDIM + nt * 16 + l15], g[nt][r]);
        }
    }
}

// ---------------- channel attention: softmax + A.V (4-way T split) ----------------
// grid (4, B*H=64), block 256
__global__ __launch_bounds__(256) void k_chan_av(
    const float* __restrict__ gbuf, const unsigned short* __restrict__ v,
    unsigned short* __restrict__ vp) {
    __shared__ short lds_a[64 * 64];
    int wave = threadIdx.x >> 6, lane = threadIdx.x & 63;
    int l15 = lane & 15, quad = lane >> 4;
    int tc = blockIdx.x, bh = blockIdx.y;
    int b = bh >> 3, h = bh & 7;
    const float sc = 0.03125f;  // 1/sqrt(1024)

    if (threadIdx.x < 64) {
        const float* gb = gbuf + bh * HDIM * HDIM + threadIdx.x * HDIM;
        float mx = -3.0e38f;
        for (int j = 0; j < 64; ++j) mx = fmaxf(mx, gb[j] * sc);
        float sum = 0.f;
        for (int j = 0; j < 64; ++j) sum += __expf(gb[j] * sc - mx);
        float inv = 1.f / sum;
        for (int j = 0; j < 64; ++j)
            lds_a[threadIdx.x * 64 + j] = (short)f2bf(__expf(gb[j] * sc - mx) * inv);
    }
    __syncthreads();

    const short* V = (const short*)v + bh * TT * HDIM;
    short8 pa[2];
#pragma unroll
    for (int kf = 0; kf < 2; ++kf)
        pa[kf] = *(const short8*)&lds_a[(wave * 16 + l15) * 64 + kf * 32 + quad * 8];

    for (int tt = 0; tt < 16; ++tt) {
        int ttile = tc * 16 + tt;
        floatx4 c = (floatx4){0.f, 0.f, 0.f, 0.f};
#pragma unroll
        for (int kf = 0; kf < 2; ++kf) {
            short8 bv = *(const short8*)(V + (ttile * 16 + l15) * HDIM + kf * 32 + quad * 8);
            c = __builtin_amdgcn_mfma_f32_16x16x32_bf16(pa[kf], bv, c, 0, 0, 0);
        }
        int t = ttile * 16 + l15;
#pragma unroll
        for (int r = 0; r < 4; ++r) {
            int crow = wave * 16 + quad * 4 + r;
            int tout = crow * 16 + (t >> 6);
            int col = 512 + ((t & 63) << 3) + h;
            vp[(b * TP + 1 + tout) * (2 * DD) + col] = f2bf(c[r]);
        }
    }
}

// ---------------- output conv: 128x128 tile, BK=32, LDS staged ----------------
// grid (T/128=8, 512/128=4, B=8)
__global__ __launch_bounds__(256) void k_out_conv(
    const unsigned short* __restrict__ vp, const unsigned short* __restrict__ w2k,
    const float* __restrict__ b2, float* __restrict__ out) {
    __shared__ short As[144 * 32];
    __shared__ short Ws[3 * 128 * 32];
    int wave = threadIdx.x >> 6, lane = threadIdx.x & 63;
    int l15 = lane & 15, quad = lane >> 4;
    int wm = wave >> 1, wn = wave & 1;
    int tb = blockIdx.x * 128;
    int cb = blockIdx.y * 128;
    int b = blockIdx.z;
    const short* A = (const short*)vp + b * TP * DD2;
    const short* W = (const short*)w2k;
    int srow = lane >> 2;
    int scol = (lane & 3) * 8;

    floatx4 acc[4][4];
#pragma unroll
    for (int mi = 0; mi < 4; ++mi)
#pragma unroll
        for (int ni = 0; ni < 4; ++ni) acc[mi][ni] = (floatx4){0.f, 0.f, 0.f, 0.f};

    for (int ci = 0; ci < DD2; ci += 32) {
        if (ci) __syncthreads();
        for (int j = wave; j < 33; j += 4) {
            if (j < 9) {
                gl2lds16(A + (tb + j * 16 + srow) * DD2 + ci + scol, &As[j * 512]);
            } else {
                int jj = j - 9;
                int k = jj >> 3;
                gl2lds16(W + (k * DD + cb + (jj & 7) * 16 + srow) * DD2 + ci + scol,
                         &Ws[jj * 512]);
            }
        }
        __syncthreads();
#pragma unroll
        for (int k = 0; k < 3; ++k) {
            short8 af[4], bf[4];
#pragma unroll
            for (int mi = 0; mi < 4; ++mi)
                af[mi] = *(const short8*)&As[(wm * 64 + mi * 16 + l15 + k) * 32 + quad * 8];
#pragma unroll
            for (int ni = 0; ni < 4; ++ni)
                bf[ni] = *(const short8*)&Ws[(k * 128 + wn * 64 + ni * 16 + l15) * 32 + quad * 8];
#pragma unroll
            for (int mi = 0; mi < 4; ++mi)
#pragma unroll
                for (int ni = 0; ni < 4; ++ni)
                    acc[mi][ni] = __builtin_amdgcn_mfma_f32_16x16x32_bf16(af[mi], bf[ni], acc[mi][ni], 0, 0, 0);
        }
    }

#pragma unroll
    for (int ni = 0; ni < 4; ++ni) {
        int co = cb + wn * 64 + ni * 16 + l15;
        float bv = b2[co];
#pragma unroll
        for (int mi = 0; mi < 4; ++mi) {
#pragma unroll
            for (int r = 0; r < 4; ++r) {
                int t = tb + wm * 64 + mi * 16 + quad * 4 + r;
                out[(b * TT + t) * DD + co] = fmaxf(acc[mi][ni][r] + bv, 0.f);
            }
        }
    }
}

extern "C" void kernel_launch(void* const* d_in, const int* in_sizes, int n_in,
                              void* d_out, int out_size, void* d_ws, size_t ws_size,
                              hipStream_t stream) {
    const float* x = (const float*)d_in[0];
    const float* w11 = (const float*)d_in[1];
    const float* b11 = (const float*)d_in[2];
    const float* w12 = (const float*)d_in[3];
    const float* b12 = (const float*)d_in[4];
    const float* w13 = (const float*)d_in[5];
    const float* b13 = (const float*)d_in[6];
    const float* w2 = (const float*)d_in[7];
    const float* b2 = (const float*)d_in[8];
    float* out = (float*)d_out;

    char* ws = (char*)d_ws;
    size_t off = 0;
    auto alloc = [&](size_t bytes) {
        void* p = ws + off;
        off += (bytes + 255) & ~(size_t)255;
        return p;
    };
    unsigned short* xp = (unsigned short*)alloc((size_t)BB * TP * DD * 2);
    unsigned short* wqkv = (unsigned short*)alloc((size_t)9 * DD * DD * 2);
    unsigned short* w2k = (unsigned short*)alloc((size_t)3 * DD * DD2 * 2);
    unsigned short* q = (unsigned short*)alloc((size_t)BB * HH * TT * HDIM * 2);
    unsigned short* qt = (unsigned short*)alloc((size_t)BB * HH * TT * HDIM * 2);
    unsigned short* k = (unsigned short*)alloc((size_t)BB * HH * TT * HDIM * 2);
    unsigned short* kt = (unsigned short*)alloc((size_t)BB * HH * TT * HDIM * 2);
    unsigned short* v = (unsigned short*)alloc((size_t)BB * HH * TT * HDIM * 2);
    unsigned short* vt = (unsigned short*)alloc((size_t)BB * HH * TT * HDIM * 2);
    float* gbuf = (float*)alloc((size_t)64 * HDIM * HDIM * 4);
    unsigned short* vp = (unsigned short*)alloc((size_t)BB * TP * 2 * DD * 2);
    (void)alloc(65536);  // guard: halo staging reads up to 14 rows past vp end

    k_convert_x<<<(BB * TP * DD + 255) / 256, 256, 0, stream>>>(x, xp);
    k_convert_wqkv<<<(3 * 3 * DD * DD + 255) / 256, 256, 0, stream>>>(w11, w12, w13, wqkv);
    k_convert_w2<<<(3 * DD * DD2 + 255) / 256, 256, 0, stream>>>(w2, w2k);
    k_zero_aux<<<(64 * HDIM * HDIM + 255) / 256, 256, 0, stream>>>(vp, gbuf);
    k_qkv_conv<<<dim3(TT / 128, DD / 128, BB * 3), 256, 0, stream>>>(xp, wqkv, b11, b12, b13,
                                                                     q, qt, k, kt, v, vt);
    k_time_attn<<<dim3(TT / 64, BB * HH), 256, 0, stream>>>(q, k, vt, vp);
    k_chan_gram<<<dim3(4, BB * HH), 256, 0, stream>>>(qt, kt, gbuf);
    k_chan_av<<<dim3(4, BB * HH), 256, 0, stream>>>(gbuf, v, vp);
    k_out_conv<<<dim3(TT / 128, DD / 128, BB), 256, 0, stream>>>(vp, w2k, b2, out);
}